// Round 1
// baseline (211.466 us; speedup 1.0000x reference)
//
#include <hip/hip_runtime.h>
#include <math.h>

#define CC   256
#define DD   16
#define HH   128
#define WWD  128
#define CRD  32
#define DSTN 16
#define DIN  64
#define LN   1024
#define NSEQ 16
#define GCH  16
#define CLEN 64

// ---------------- workspace layout (floats) ----------------
constexpr size_t NTOK = (size_t)NSEQ * LN;                         // 16384 tokens
constexpr size_t OFF_TOKN = 0;                                     // [16][1024][32]
constexpr size_t OFF_XS   = OFF_TOKN + NTOK*CRD;                   // [2][16][1024][64]
constexpr size_t OFF_DT   = OFF_XS   + 2*NTOK*DIN;
constexpr size_t OFF_ZS   = OFF_DT   + 2*NTOK*DIN;
constexpr size_t OFF_B    = OFF_ZS   + 2*NTOK*DIN;                 // [2][16][1024][16]
constexpr size_t OFF_C    = OFF_B    + 2*NTOK*DSTN;
constexpr size_t OFF_Y    = OFF_C    + 2*NTOK*DSTN;                // [2][16][1024][64]
constexpr size_t OFF_P    = OFF_Y    + 2*NTOK*DIN;                 // [2][16][16][64][16]
constexpr size_t OFF_HE   = OFF_P    + 2*(size_t)NSEQ*GCH*DIN*DSTN;
constexpr size_t OFF_YM   = OFF_HE   + 2*(size_t)NSEQ*GCH*DIN*DSTN; // [16][1024][32]
constexpr size_t OFF_INWT = OFF_YM   + NTOK*CRD;                   // [2][32][128]
constexpr size_t OFF_XPT  = OFF_INWT + 2*(size_t)CRD*128;          // [2][64][34]
constexpr size_t OFF_OWT  = OFF_XPT  + 2*(size_t)DIN*34;           // [2][64][32]
constexpr size_t OFF_AN   = OFF_OWT  + 2*(size_t)DIN*CRD;          // [2][64][16]
constexpr size_t OFF_WINT = OFF_AN   + 2*(size_t)DIN*DSTN;         // [256][32]
constexpr size_t WS_FLOATS = OFF_WINT + (size_t)CC*CRD;            // ~11.6M floats (~46 MB)

__device__ __forceinline__ float siluf(float x) { return x / (1.0f + __expf(-x)); }

// ---------------- K0: weight transposes + A precompute ----------------
__global__ void k0_prep(const float* __restrict__ inw_f, const float* __restrict__ inw_b,
                        const float* __restrict__ xp_f,  const float* __restrict__ xp_b,
                        const float* __restrict__ ow_f,  const float* __restrict__ ow_b,
                        const float* __restrict__ al_f,  const float* __restrict__ al_b,
                        const float* __restrict__ w_in,
                        float* __restrict__ inwT, float* __restrict__ xpT,
                        float* __restrict__ owT,  float* __restrict__ An,
                        float* __restrict__ winT) {
  int t = blockIdx.x*blockDim.x + threadIdx.x;
  int nth = gridDim.x*blockDim.x;
  for (int i = t; i < 2*CRD*128; i += nth) {           // inwT[dir][d][e] = in_w[e][d]
    int dir = i / (CRD*128); int rem = i - dir*(CRD*128);
    int d = rem >> 7; int e = rem & 127;
    inwT[i] = (dir ? inw_b : inw_f)[e*CRD + d];
  }
  for (int i = t; i < 2*DIN*34; i += nth) {            // xpT[dir][d][e] = xproj_w[e][d]
    int dir = i / (DIN*34); int rem = i - dir*(DIN*34);
    int d = rem / 34; int e = rem - d*34;
    xpT[i] = (dir ? xp_b : xp_f)[e*DIN + d];
  }
  for (int i = t; i < 2*DIN*CRD; i += nth) {           // owT[dir][d][r] = out_w[r][d]
    int dir = i / (DIN*CRD); int rem = i - dir*(DIN*CRD);
    int d = rem >> 5; int r = rem & 31;
    owT[i] = (dir ? ow_b : ow_f)[r*DIN + d];
  }
  for (int i = t; i < 2*DIN*DSTN; i += nth) {          // An[dir][d][s] = -exp(A_log)
    int dir = i / (DIN*DSTN); int rem = i - dir*(DIN*DSTN);
    An[i] = -expf((dir ? al_b : al_f)[rem]);
  }
  for (int i = t; i < CC*CRD; i += nth) {              // winT[c][r] = w_in[r][c]
    int c = i >> 5; int r = i & 31;
    winT[i] = w_in[r*CC + c];
  }
}

// ---------------- K1: subsampled 256->32 projection + LayerNorm ----------------
__global__ __launch_bounds__(256) void k1_token_ln(
    const float* __restrict__ x, const float* __restrict__ winT,
    const float* __restrict__ ln_w, const float* __restrict__ ln_b,
    float* __restrict__ tokn) {
  __shared__ float xv[CC*CRD];     // [c][ws] 32KB
  __shared__ float zt[CRD][33];    // [r][ws] padded
  __shared__ float mu_s[32], rs_s[32];
  int b = blockIdx.x;              // 512 = 16 d * 32 hs
  int d = b >> 5, hs = b & 31;
  int t = threadIdx.x;
  // load x[c, d, 4hs, 4ws] -> xv[c][ws]
  {
    int wsx = t & 31, cg = t >> 5;
    const float* xbase = x + ((size_t)d*HH + 4*hs)*WWD + 4*wsx;
    for (int i = 0; i < 32; ++i) {
      int c = cg*32 + i;
      xv[c*CRD + wsx] = xbase[(size_t)c*DD*HH*WWD];
    }
  }
  __syncthreads();
  // z[r][ws] = sum_c winT[c][r] * xv[c][ws] ; thread: r = t&31, 4 ws values
  {
    int r = t & 31, wq = t >> 5;
    float a0=0.f,a1=0.f,a2=0.f,a3=0.f;
    #pragma unroll 8
    for (int c = 0; c < CC; ++c) {
      float w = winT[c*CRD + r];
      float4 xq = *(const float4*)(xv + c*CRD + wq*4);
      a0 = fmaf(w, xq.x, a0); a1 = fmaf(w, xq.y, a1);
      a2 = fmaf(w, xq.z, a2); a3 = fmaf(w, xq.w, a3);
    }
    zt[r][wq*4+0] = a0; zt[r][wq*4+1] = a1;
    zt[r][wq*4+2] = a2; zt[r][wq*4+3] = a3;
  }
  __syncthreads();
  if (t < 32) {                    // LN stats for token ws=t
    float mu = 0.f;
    for (int r = 0; r < 32; ++r) mu += zt[r][t];
    mu *= (1.0f/32.0f);
    float var = 0.f;
    for (int r = 0; r < 32; ++r) { float dl = zt[r][t]-mu; var = fmaf(dl, dl, var); }
    var *= (1.0f/32.0f);
    mu_s[t] = mu; rs_s[t] = 1.0f/sqrtf(var + 1e-5f);
  }
  __syncthreads();
  float* outp = tokn + ((size_t)d*LN + hs*32)*CRD;
  for (int it = t; it < 1024; it += 256) {
    int w2 = it >> 5, r2 = it & 31;
    outp[it] = (zt[r2][w2]-mu_s[w2])*rs_s[w2]*ln_w[r2] + ln_b[r2];
  }
}

// ---------------- K2: per-direction pre-scan pipeline ----------------
__global__ __launch_bounds__(256) void k2_prescan(
    const float* __restrict__ tokn, const float* __restrict__ ws_inwT,
    const float* __restrict__ ws_xpT,
    const float* __restrict__ cw_f, const float* __restrict__ cb_f,
    const float* __restrict__ dtw_f, const float* __restrict__ dtb_f,
    const float* __restrict__ cw_b, const float* __restrict__ cb_b,
    const float* __restrict__ dtw_b, const float* __restrict__ dtb_b,
    float* __restrict__ xs_ws, float* __restrict__ dt_ws, float* __restrict__ zs_ws,
    float* __restrict__ B_ws, float* __restrict__ C_ws) {
  __shared__ float tk[67*CRD];      // tokens l0-3 .. l0+63
  __shared__ float xr[67*DIN];      // raw x (pre-conv)
  __shared__ float xsld[64*DIN];    // silu(conv(x))
  __shared__ float dbc[64*36];      // padded 34->36
  int b = blockIdx.x;               // 512 = 2 dir * 16 n * 16 ch
  int dir = b >> 8, n = (b >> 4) & 15, ch = b & 15;
  int l0 = ch*CLEN;
  int t = threadIdx.x;
  const float* inwT = ws_inwT + (size_t)dir*CRD*128;
  const float* xpT  = ws_xpT  + (size_t)dir*DIN*34;
  const float* cw  = dir ? cw_b  : cw_f;
  const float* cb  = dir ? cb_b  : cb_f;
  const float* dtw = dir ? dtw_b : dtw_f;
  const float* dtb = dir ? dtb_b : dtb_f;
  size_t segbase = ((size_t)dir*NSEQ + n)*LN + l0;   // token index base for outputs

  for (int i = t; i < 67*CRD; i += 256) {
    int row = i >> 5, col = i & 31;
    int lb = l0 - 3 + row;
    float v = 0.f;
    if (lb >= 0) {
      int lo = dir ? (LN-1-lb) : lb;
      v = tokn[((size_t)n*LN + lo)*CRD + col];
    }
    tk[i] = v;
  }
  __syncthreads();
  // phase A: xr[row][e] = sum_d tk[row][d]*inwT[d][e]   (67 rows, e<64)
  for (int i = t; i < 67*DIN; i += 256) {
    int row = i >> 6, e = i & 63;
    float acc = 0.f;
    const float* tkr = tk + row*CRD;
    #pragma unroll 8
    for (int d = 0; d < CRD; ++d) acc = fmaf(tkr[d], inwT[d*128 + e], acc);
    xr[i] = acc;
  }
  // phase B: z-gate -> silu -> global  (64 rows, e 64..127)
  for (int i = t; i < 64*DIN; i += 256) {
    int row = i >> 6, e = i & 63;
    float acc = 0.f;
    const float* tkr = tk + (row+3)*CRD;
    #pragma unroll 8
    for (int d = 0; d < CRD; ++d) acc = fmaf(tkr[d], inwT[d*128 + 64 + e], acc);
    zs_ws[(segbase + row)*DIN + e] = siluf(acc);
  }
  __syncthreads();
  // phase C: depthwise conv4 + silu
  for (int i = t; i < 64*DIN; i += 256) {
    int r = i >> 6, d = i & 63;
    float acc = cb[d];
    #pragma unroll
    for (int k = 0; k < 4; ++k) acc = fmaf(cw[d*4+k], xr[(r+k)*DIN + d], acc);
    float v = siluf(acc);
    xsld[i] = v;
    xs_ws[(segbase + r)*DIN + d] = v;
  }
  __syncthreads();
  // phase D1: dbc[r][e] = sum_d xs[r][d]*xpT[d][e]  (e<34)
  for (int i = t; i < 64*34; i += 256) {
    int r = i / 34, e = i - r*34;
    float acc = 0.f;
    const float* xsr = xsld + r*DIN;
    #pragma unroll 8
    for (int d = 0; d < DIN; ++d) acc = fmaf(xsr[d], xpT[d*34 + e], acc);
    dbc[r*36 + e] = acc;
  }
  __syncthreads();
  // phase D2: dt = softplus(dbc[0:2] @ dt_w^T + dt_b)
  for (int i = t; i < 64*DIN; i += 256) {
    int r = i >> 6, d = i & 63;
    float z = fmaf(dbc[r*36+0], dtw[d*2+0], fmaf(dbc[r*36+1], dtw[d*2+1], dtb[d]));
    float sp = (z > 20.f) ? z : log1pf(__expf(z));
    dt_ws[(segbase + r)*DIN + d] = sp;
  }
  // B / C extraction
  for (int i = t; i < 64*DSTN; i += 256) {
    int r = i >> 4, s = i & 15;
    B_ws[(segbase + r)*DSTN + s] = dbc[r*36 + 2 + s];
  }
  for (int i = t; i < 64*DSTN; i += 256) {
    int r = i >> 4, s = i & 15;
    C_ws[(segbase + r)*DSTN + s] = dbc[r*36 + 18 + s];
  }
}

// ---------------- K3a: chunk transitions (P, h_end from h=0) ----------------
__global__ __launch_bounds__(256) void k3a_chunk(
    const float* __restrict__ dt_ws, const float* __restrict__ xs_ws,
    const float* __restrict__ B_ws, const float* __restrict__ An,
    float* __restrict__ P_ws, float* __restrict__ hend_ws) {
  int b = blockIdx.x;               // 512 = 2*16*16
  int dir = b >> 8, n = (b >> 4) & 15, g = b & 15;
  int t = threadIdx.x;
  int d = t >> 2, sq = t & 3;
  const float* Ap = An + ((size_t)dir*DIN + d)*DSTN + sq*4;
  float A0 = Ap[0], A1 = Ap[1], A2 = Ap[2], A3 = Ap[3];
  float h0=0.f,h1=0.f,h2=0.f,h3=0.f, P0=1.f,P1=1.f,P2=1.f,P3=1.f;
  size_t base = ((size_t)dir*NSEQ + n)*LN + g*CLEN;
  const float* dtp = dt_ws + base*DIN + d;
  const float* xsp = xs_ws + base*DIN + d;
  const float4* Bp = (const float4*)(B_ws + base*DSTN) + sq;
  for (int i = 0; i < CLEN; ++i) {
    float dtv = dtp[i*DIN];
    float xv  = xsp[i*DIN];
    float4 Bv = Bp[i*4];
    float dtx = dtv*xv;
    float a0 = __expf(dtv*A0), a1 = __expf(dtv*A1);
    float a2 = __expf(dtv*A2), a3 = __expf(dtv*A3);
    P0 *= a0; P1 *= a1; P2 *= a2; P3 *= a3;
    h0 = fmaf(a0, h0, dtx*Bv.x); h1 = fmaf(a1, h1, dtx*Bv.y);
    h2 = fmaf(a2, h2, dtx*Bv.z); h3 = fmaf(a3, h3, dtx*Bv.w);
  }
  size_t pbase = ((((size_t)dir*NSEQ + n)*GCH + g)*DIN + d)*DSTN + sq*4;
  *(float4*)(P_ws + pbase)    = make_float4(P0,P1,P2,P3);
  *(float4*)(hend_ws + pbase) = make_float4(h0,h1,h2,h3);
}

// ---------------- K3b: full scan with composed h_in + gating ----------------
__global__ __launch_bounds__(256) void k3b_scan(
    const float* __restrict__ dt_ws, const float* __restrict__ xs_ws,
    const float* __restrict__ B_ws, const float* __restrict__ C_ws,
    const float* __restrict__ zs_ws, const float* __restrict__ An,
    const float* __restrict__ P_ws, const float* __restrict__ hend_ws,
    const float* __restrict__ D_f, const float* __restrict__ D_b,
    float* __restrict__ y_ws) {
  int b = blockIdx.x;               // 512
  int dir = b >> 8, n = (b >> 4) & 15, g = b & 15;
  int t = threadIdx.x;
  int d = t >> 2, sq = t & 3;
  const float* Ap = An + ((size_t)dir*DIN + d)*DSTN + sq*4;
  float A0 = Ap[0], A1 = Ap[1], A2 = Ap[2], A3 = Ap[3];
  float h0=0.f,h1=0.f,h2=0.f,h3=0.f;
  for (int gp = 0; gp < g; ++gp) {   // compose transitions of earlier chunks
    size_t pb = ((((size_t)dir*NSEQ + n)*GCH + gp)*DIN + d)*DSTN + sq*4;
    float4 Pv = *(const float4*)(P_ws + pb);
    float4 Hv = *(const float4*)(hend_ws + pb);
    h0 = fmaf(Pv.x, h0, Hv.x); h1 = fmaf(Pv.y, h1, Hv.y);
    h2 = fmaf(Pv.z, h2, Hv.z); h3 = fmaf(Pv.w, h3, Hv.w);
  }
  float Dp = (dir ? D_b : D_f)[d];
  size_t base = ((size_t)dir*NSEQ + n)*LN + g*CLEN;
  const float* dtp = dt_ws + base*DIN + d;
  const float* xsp = xs_ws + base*DIN + d;
  const float* zsp = zs_ws + base*DIN + d;
  const float4* Bp = (const float4*)(B_ws + base*DSTN) + sq;
  const float4* Cp = (const float4*)(C_ws + base*DSTN) + sq;
  float* yp = y_ws + base*DIN + d;
  for (int i = 0; i < CLEN; ++i) {
    float dtv = dtp[i*DIN];
    float xv  = xsp[i*DIN];
    float4 Bv = Bp[i*4];
    float4 Cv = Cp[i*4];
    float dtx = dtv*xv;
    float a0 = __expf(dtv*A0), a1 = __expf(dtv*A1);
    float a2 = __expf(dtv*A2), a3 = __expf(dtv*A3);
    h0 = fmaf(a0, h0, dtx*Bv.x); h1 = fmaf(a1, h1, dtx*Bv.y);
    h2 = fmaf(a2, h2, dtx*Bv.z); h3 = fmaf(a3, h3, dtx*Bv.w);
    float p = h0*Cv.x + h1*Cv.y + h2*Cv.z + h3*Cv.w;
    p += __shfl_xor(p, 1);
    p += __shfl_xor(p, 2);
    if (sq == 0) {
      float zv = zsp[i*DIN];
      yp[i*DIN] = (p + Dp*xv)*zv;
    }
  }
}

// ---------------- K4: combine dirs + 64->32 output projection ----------------
__global__ __launch_bounds__(256) void k4_combine(
    const float* __restrict__ y_ws, const float* __restrict__ owT,
    float* __restrict__ ym) {
  int b = blockIdx.x;               // 2048 blocks * 8 tokens
  int t = threadIdx.x;
  int tok = t >> 5, r = t & 31;
  int gl = b*8 + tok;               // 0..16383
  int n = gl >> 10, l = gl & 1023;
  const float* yf = y_ws + ((size_t)n*LN + l)*DIN;
  const float* yb = y_ws + ((size_t)(NSEQ + n)*LN + (LN-1-l))*DIN;
  const float* owf = owT;
  const float* owb = owT + DIN*CRD;
  float acc = 0.f;
  #pragma unroll 8
  for (int d2 = 0; d2 < DIN; ++d2) {
    acc = fmaf(yf[d2], owf[d2*CRD + r], acc);
    acc = fmaf(yb[d2], owb[d2*CRD + r], acc);
  }
  ym[(size_t)gl*CRD + r] = 0.5f*acc;
}

// ---------------- K5: 32->256 projection + 4x4 upsample (write-bound) ----------------
__global__ __launch_bounds__(256) void k5_out(
    const float* __restrict__ ym, const float* __restrict__ w_out,
    float* __restrict__ out) {
  __shared__ float wo[CC*CRD];      // 32KB
  __shared__ float frp[32*33];      // padded feat tile
  int b = blockIdx.x;               // 512 = 16 d * 32 hs
  int d = b >> 5, hs = b & 31;
  int t = threadIdx.x;
  for (int i = t; i < CC*CRD; i += 256) wo[i] = w_out[i];
  const float* fb = ym + ((size_t)d*LN + hs*32)*CRD;
  for (int i = t; i < 1024; i += 256) {
    int wq = i >> 5, r = i & 31;
    frp[wq*33 + r] = fb[i];
  }
  __syncthreads();
  int q = t & 31, cg = t >> 5;
  const float* fr = frp + q*33;
  for (int ci = 0; ci < 32; ++ci) {
    int c = cg*32 + ci;
    const float* wr = wo + c*CRD;
    float acc = 0.f;
    #pragma unroll 8
    for (int r = 0; r < 32; ++r) acc = fmaf(wr[r], fr[r], acc);
    float4 v = make_float4(acc, acc, acc, acc);
    size_t rowbase = (((size_t)c*DD + d)*HH + 4*hs)*WWD + 4*q;
    *(float4*)(out + rowbase)           = v;
    *(float4*)(out + rowbase +   WWD)   = v;
    *(float4*)(out + rowbase + 2*WWD)   = v;
    *(float4*)(out + rowbase + 3*WWD)   = v;
  }
}

extern "C" void kernel_launch(void* const* d_in, const int* in_sizes, int n_in,
                              void* d_out, int out_size, void* d_ws, size_t ws_size,
                              hipStream_t stream) {
  const float* x      = (const float*)d_in[0];
  const float* w_in   = (const float*)d_in[1];
  const float* w_out  = (const float*)d_in[2];
  const float* ln_w   = (const float*)d_in[3];
  const float* ln_b   = (const float*)d_in[4];
  const float* mf_in_w   = (const float*)d_in[5];
  const float* mf_conv_w = (const float*)d_in[6];
  const float* mf_conv_b = (const float*)d_in[7];
  const float* mf_xproj  = (const float*)d_in[8];
  const float* mf_dt_w   = (const float*)d_in[9];
  const float* mf_dt_b   = (const float*)d_in[10];
  const float* mf_A_log  = (const float*)d_in[11];
  const float* mf_D      = (const float*)d_in[12];
  const float* mf_out_w  = (const float*)d_in[13];
  const float* mb_in_w   = (const float*)d_in[14];
  const float* mb_conv_w = (const float*)d_in[15];
  const float* mb_conv_b = (const float*)d_in[16];
  const float* mb_xproj  = (const float*)d_in[17];
  const float* mb_dt_w   = (const float*)d_in[18];
  const float* mb_dt_b   = (const float*)d_in[19];
  const float* mb_A_log  = (const float*)d_in[20];
  const float* mb_D      = (const float*)d_in[21];
  const float* mb_out_w  = (const float*)d_in[22];

  float* ws   = (float*)d_ws;
  float* tokn = ws + OFF_TOKN;
  float* xs   = ws + OFF_XS;
  float* dtw_ = ws + OFF_DT;
  float* zs   = ws + OFF_ZS;
  float* Bw   = ws + OFF_B;
  float* Cw   = ws + OFF_C;
  float* yw   = ws + OFF_Y;
  float* Pw   = ws + OFF_P;
  float* He   = ws + OFF_HE;
  float* ym   = ws + OFF_YM;
  float* inwT = ws + OFF_INWT;
  float* xpT  = ws + OFF_XPT;
  float* owT  = ws + OFF_OWT;
  float* An   = ws + OFF_AN;
  float* winT = ws + OFF_WINT;

  k0_prep<<<32, 256, 0, stream>>>(mf_in_w, mb_in_w, mf_xproj, mb_xproj,
                                  mf_out_w, mb_out_w, mf_A_log, mb_A_log,
                                  w_in, inwT, xpT, owT, An, winT);
  k1_token_ln<<<512, 256, 0, stream>>>(x, winT, ln_w, ln_b, tokn);
  k2_prescan<<<512, 256, 0, stream>>>(tokn, inwT, xpT,
                                      mf_conv_w, mf_conv_b, mf_dt_w, mf_dt_b,
                                      mb_conv_w, mb_conv_b, mb_dt_w, mb_dt_b,
                                      xs, dtw_, zs, Bw, Cw);
  k3a_chunk<<<512, 256, 0, stream>>>(dtw_, xs, Bw, An, Pw, He);
  k3b_scan<<<512, 256, 0, stream>>>(dtw_, xs, Bw, Cw, zs, An, Pw, He,
                                    mf_D, mb_D, yw);
  k4_combine<<<2048, 256, 0, stream>>>(yw, owT, ym);
  k5_out<<<512, 256, 0, stream>>>(ym, w_out, (float*)d_out);
}

// Round 2
// 195.965 us; speedup vs baseline: 1.0791x; 1.0791x over previous
//
#include <hip/hip_runtime.h>
#include <math.h>

#define CC   256
#define DD   16
#define HH   128
#define WWD  128
#define CRD  32
#define DSTN 16
#define DIN  64
#define LN   1024
#define NSEQ 16
#define GCH  16
#define CLEN 64

// ---------------- workspace layout (floats) ----------------
constexpr size_t NTOK = (size_t)NSEQ * LN;                         // 16384 tokens
constexpr size_t OFF_TOKN = 0;                                     // [16][1024][32]
constexpr size_t OFF_XS   = OFF_TOKN + NTOK*CRD;                   // [2][16][1024][64]
constexpr size_t OFF_DT   = OFF_XS   + 2*NTOK*DIN;
constexpr size_t OFF_ZS   = OFF_DT   + 2*NTOK*DIN;
constexpr size_t OFF_B    = OFF_ZS   + 2*NTOK*DIN;                 // [2][16][1024][16]
constexpr size_t OFF_C    = OFF_B    + 2*NTOK*DSTN;
constexpr size_t OFF_Y    = OFF_C    + 2*NTOK*DSTN;                // [2][16][1024][64]
constexpr size_t OFF_P    = OFF_Y    + 2*NTOK*DIN;                 // [2][16][16][64][16]
constexpr size_t OFF_HE   = OFF_P    + 2*(size_t)NSEQ*GCH*DIN*DSTN;
constexpr size_t OFF_INWT = OFF_HE   + 2*(size_t)NSEQ*GCH*DIN*DSTN; // [2][32][128]
constexpr size_t OFF_XPT  = OFF_INWT + 2*(size_t)CRD*128;          // [2][64][34]
constexpr size_t OFF_OWT  = OFF_XPT  + 2*(size_t)DIN*34;           // [2][64][32]
constexpr size_t OFF_AN   = OFF_OWT  + 2*(size_t)DIN*CRD;          // [2][64][16]
constexpr size_t OFF_WINT = OFF_AN   + 2*(size_t)DIN*DSTN;         // [256][32]

__device__ __forceinline__ float siluf(float x) { return x / (1.0f + __expf(-x)); }

// ---------------- K0: weight transposes + A precompute ----------------
__global__ void bm3d_k0_prep(const float* __restrict__ inw_f, const float* __restrict__ inw_b,
                        const float* __restrict__ xp_f,  const float* __restrict__ xp_b,
                        const float* __restrict__ ow_f,  const float* __restrict__ ow_b,
                        const float* __restrict__ al_f,  const float* __restrict__ al_b,
                        const float* __restrict__ w_in,
                        float* __restrict__ inwT, float* __restrict__ xpT,
                        float* __restrict__ owT,  float* __restrict__ An,
                        float* __restrict__ winT) {
  int t = blockIdx.x*blockDim.x + threadIdx.x;
  int nth = gridDim.x*blockDim.x;
  for (int i = t; i < 2*CRD*128; i += nth) {           // inwT[dir][d][e] = in_w[e][d]
    int dir = i / (CRD*128); int rem = i - dir*(CRD*128);
    int d = rem >> 7; int e = rem & 127;
    inwT[i] = (dir ? inw_b : inw_f)[e*CRD + d];
  }
  for (int i = t; i < 2*DIN*34; i += nth) {            // xpT[dir][d][e] = xproj_w[e][d]
    int dir = i / (DIN*34); int rem = i - dir*(DIN*34);
    int d = rem / 34; int e = rem - d*34;
    xpT[i] = (dir ? xp_b : xp_f)[e*DIN + d];
  }
  for (int i = t; i < 2*DIN*CRD; i += nth) {           // owT[dir][d][r] = out_w[r][d]
    int dir = i / (DIN*CRD); int rem = i - dir*(DIN*CRD);
    int d = rem >> 5; int r = rem & 31;
    owT[i] = (dir ? ow_b : ow_f)[r*DIN + d];
  }
  for (int i = t; i < 2*DIN*DSTN; i += nth) {          // An[dir][d][s] = -exp(A_log)
    int dir = i / (DIN*DSTN); int rem = i - dir*(DIN*DSTN);
    An[i] = -expf((dir ? al_b : al_f)[rem]);
  }
  for (int i = t; i < CC*CRD; i += nth) {              // winT[c][r] = w_in[r][c]
    int c = i >> 5; int r = i & 31;
    winT[i] = w_in[r*CC + c];
  }
}

// ---------------- K1: subsampled 256->32 projection + LayerNorm ----------------
__global__ __launch_bounds__(256) void bm3d_k1_token_ln(
    const float* __restrict__ x, const float* __restrict__ winT,
    const float* __restrict__ ln_w, const float* __restrict__ ln_b,
    float* __restrict__ tokn) {
  __shared__ float xv[CC*CRD];     // [c][ws] 32KB
  __shared__ float zt[CRD][33];    // [r][ws] padded
  __shared__ float mu_s[32], rs_s[32];
  int b = blockIdx.x;              // 512 = 16 d * 32 hs
  int d = b >> 5, hs = b & 31;
  int t = threadIdx.x;
  // load x[c, d, 4hs, 4ws] -> xv[c][ws]; float4 per row, keep .x (full line fetched anyway)
  {
    int wsx = t & 31, cg = t >> 5;
    const float4* xbase = (const float4*)(x + ((size_t)d*HH + 4*hs)*WWD) + wsx;
    #pragma unroll 8
    for (int i = 0; i < 32; ++i) {
      int c = cg*32 + i;
      xv[c*CRD + wsx] = xbase[(size_t)c*(DD*HH*WWD/4)].x;
    }
  }
  __syncthreads();
  // z[r][ws] = sum_c winT[c][r] * xv[c][ws] ; thread: r = t&31, 4 ws values
  {
    int r = t & 31, wq = t >> 5;
    float a0=0.f,a1=0.f,a2=0.f,a3=0.f;
    #pragma unroll 8
    for (int c = 0; c < CC; ++c) {
      float w = winT[c*CRD + r];
      float4 xq = *(const float4*)(xv + c*CRD + wq*4);
      a0 = fmaf(w, xq.x, a0); a1 = fmaf(w, xq.y, a1);
      a2 = fmaf(w, xq.z, a2); a3 = fmaf(w, xq.w, a3);
    }
    zt[r][wq*4+0] = a0; zt[r][wq*4+1] = a1;
    zt[r][wq*4+2] = a2; zt[r][wq*4+3] = a3;
  }
  __syncthreads();
  if (t < 32) {                    // LN stats for token ws=t
    float mu = 0.f;
    for (int r = 0; r < 32; ++r) mu += zt[r][t];
    mu *= (1.0f/32.0f);
    float var = 0.f;
    for (int r = 0; r < 32; ++r) { float dl = zt[r][t]-mu; var = fmaf(dl, dl, var); }
    var *= (1.0f/32.0f);
    mu_s[t] = mu; rs_s[t] = 1.0f/sqrtf(var + 1e-5f);
  }
  __syncthreads();
  float* outp = tokn + ((size_t)d*LN + hs*32)*CRD;
  for (int it = t; it < 1024; it += 256) {
    int w2 = it >> 5, r2 = it & 31;
    outp[it] = (zt[r2][w2]-mu_s[w2])*rs_s[w2]*ln_w[r2] + ln_b[r2];
  }
}

// ---------------- K2: pre-scan pipeline + fused chunk-local scan ----------------
__global__ __launch_bounds__(256) void bm3d_k2_prescan_chunk(
    const float* __restrict__ tokn, const float* __restrict__ ws_inwT,
    const float* __restrict__ ws_xpT,
    const float* __restrict__ cw_f, const float* __restrict__ cb_f,
    const float* __restrict__ dtw_f, const float* __restrict__ dtb_f,
    const float* __restrict__ cw_b, const float* __restrict__ cb_b,
    const float* __restrict__ dtw_b, const float* __restrict__ dtb_b,
    const float* __restrict__ An,
    float* __restrict__ xs_ws, float* __restrict__ dt_ws, float* __restrict__ zs_ws,
    float* __restrict__ B_ws, float* __restrict__ C_ws,
    float* __restrict__ P_ws, float* __restrict__ hend_ws) {
  __shared__ float tk[67*CRD];      // tokens l0-3 .. l0+63 (8.6KB)
  __shared__ float xr[67*DIN];      // raw x pre-conv (17.2KB)
  __shared__ float xsld[64*DIN];    // silu(conv(x)) (16KB)
  __shared__ float dbc[64*36];      // padded 34->36 (9.2KB)
  __shared__ float dts[64*DIN];     // softplus dt (16KB)
  int b = blockIdx.x;               // 512 = 2 dir * 16 n * 16 g
  int dir = b >> 8, n = (b >> 4) & 15, g = b & 15;
  int l0 = g*CLEN;
  int t = threadIdx.x;
  const float* inwT = ws_inwT + (size_t)dir*CRD*128;
  const float* xpT  = ws_xpT  + (size_t)dir*DIN*34;
  const float* cw  = dir ? cw_b  : cw_f;
  const float* cb  = dir ? cb_b  : cb_f;
  const float* dtw = dir ? dtw_b : dtw_f;
  const float* dtb = dir ? dtb_b : dtb_f;
  size_t segbase = ((size_t)dir*NSEQ + n)*LN + l0;

  for (int i = t; i < 67*CRD; i += 256) {
    int row = i >> 5, col = i & 31;
    int lb = l0 - 3 + row;
    float v = 0.f;
    if (lb >= 0) {
      int lo = dir ? (LN-1-lb) : lb;
      v = tokn[((size_t)n*LN + lo)*CRD + col];
    }
    tk[i] = v;
  }
  __syncthreads();
  // phase A: xr[row][e] = sum_d tk[row][d]*inwT[d][e]
  for (int i = t; i < 67*DIN; i += 256) {
    int row = i >> 6, e = i & 63;
    float acc = 0.f;
    const float* tkr = tk + row*CRD;
    #pragma unroll 8
    for (int d = 0; d < CRD; ++d) acc = fmaf(tkr[d], inwT[d*128 + e], acc);
    xr[i] = acc;
  }
  // phase B: z-gate -> silu -> global
  for (int i = t; i < 64*DIN; i += 256) {
    int row = i >> 6, e = i & 63;
    float acc = 0.f;
    const float* tkr = tk + (row+3)*CRD;
    #pragma unroll 8
    for (int d = 0; d < CRD; ++d) acc = fmaf(tkr[d], inwT[d*128 + 64 + e], acc);
    zs_ws[(segbase + row)*DIN + e] = siluf(acc);
  }
  __syncthreads();
  // phase C: depthwise conv4 + silu
  for (int i = t; i < 64*DIN; i += 256) {
    int r = i >> 6, d = i & 63;
    float acc = cb[d];
    #pragma unroll
    for (int k = 0; k < 4; ++k) acc = fmaf(cw[d*4+k], xr[(r+k)*DIN + d], acc);
    float v = siluf(acc);
    xsld[i] = v;
    xs_ws[(segbase + r)*DIN + d] = v;
  }
  __syncthreads();
  // phase D1: dbc[r][e] = sum_d xs[r][d]*xpT[d][e]  (e<34)
  for (int i = t; i < 64*34; i += 256) {
    int r = i / 34, e = i - r*34;
    float acc = 0.f;
    const float* xsr = xsld + r*DIN;
    #pragma unroll 8
    for (int d = 0; d < DIN; ++d) acc = fmaf(xsr[d], xpT[d*34 + e], acc);
    dbc[r*36 + e] = acc;
  }
  __syncthreads();
  // phase D2: dt = softplus(dbc[0:2] @ dt_w^T + dt_b) -> dts + global
  for (int i = t; i < 64*DIN; i += 256) {
    int r = i >> 6, d = i & 63;
    float z = fmaf(dbc[r*36+0], dtw[d*2+0], fmaf(dbc[r*36+1], dtw[d*2+1], dtb[d]));
    float sp = (z > 20.f) ? z : log1pf(__expf(z));
    dts[i] = sp;
    dt_ws[(segbase + r)*DIN + d] = sp;
  }
  // B / C extraction to global (for the full-scan kernel)
  for (int i = t; i < 64*DSTN; i += 256) {
    int r = i >> 4, s = i & 15;
    B_ws[(segbase + r)*DSTN + s] = dbc[r*36 + 2 + s];
  }
  for (int i = t; i < 64*DSTN; i += 256) {
    int r = i >> 4, s = i & 15;
    C_ws[(segbase + r)*DSTN + s] = dbc[r*36 + 18 + s];
  }
  __syncthreads();
  // fused chunk-local scan: P (decay product) and h_end (from h=0), all from LDS
  {
    int d = t >> 2, sq = t & 3;
    const float* Ap = An + ((size_t)dir*DIN + d)*DSTN + sq*4;
    float A0 = Ap[0], A1 = Ap[1], A2 = Ap[2], A3 = Ap[3];
    float h0=0.f,h1=0.f,h2=0.f,h3=0.f, P0=1.f,P1=1.f,P2=1.f,P3=1.f;
    #pragma unroll 4
    for (int i = 0; i < CLEN; ++i) {
      float dtv = dts[i*DIN + d];
      float xv  = xsld[i*DIN + d];
      float b0 = dbc[i*36 + 2 + sq*4 + 0];
      float b1 = dbc[i*36 + 2 + sq*4 + 1];
      float b2 = dbc[i*36 + 2 + sq*4 + 2];
      float b3 = dbc[i*36 + 2 + sq*4 + 3];
      float dtx = dtv*xv;
      float a0 = __expf(dtv*A0), a1 = __expf(dtv*A1);
      float a2 = __expf(dtv*A2), a3 = __expf(dtv*A3);
      P0 *= a0; P1 *= a1; P2 *= a2; P3 *= a3;
      h0 = fmaf(a0, h0, dtx*b0); h1 = fmaf(a1, h1, dtx*b1);
      h2 = fmaf(a2, h2, dtx*b2); h3 = fmaf(a3, h3, dtx*b3);
    }
    size_t pbase = ((((size_t)dir*NSEQ + n)*GCH + g)*DIN + d)*DSTN + sq*4;
    *(float4*)(P_ws + pbase)    = make_float4(P0,P1,P2,P3);
    *(float4*)(hend_ws + pbase) = make_float4(h0,h1,h2,h3);
  }
}

// ---------------- K3: full scan with composed h_in + gating ----------------
__global__ __launch_bounds__(256) void bm3d_k3_scan(
    const float* __restrict__ dt_ws, const float* __restrict__ xs_ws,
    const float* __restrict__ B_ws, const float* __restrict__ C_ws,
    const float* __restrict__ zs_ws, const float* __restrict__ An,
    const float* __restrict__ P_ws, const float* __restrict__ hend_ws,
    const float* __restrict__ D_f, const float* __restrict__ D_b,
    float* __restrict__ y_ws) {
  int b = blockIdx.x;               // 512
  int dir = b >> 8, n = (b >> 4) & 15, g = b & 15;
  int t = threadIdx.x;
  int d = t >> 2, sq = t & 3;
  const float* Ap = An + ((size_t)dir*DIN + d)*DSTN + sq*4;
  float A0 = Ap[0], A1 = Ap[1], A2 = Ap[2], A3 = Ap[3];
  float h0=0.f,h1=0.f,h2=0.f,h3=0.f;
  for (int gp = 0; gp < g; ++gp) {   // compose transitions of earlier chunks
    size_t pb = ((((size_t)dir*NSEQ + n)*GCH + gp)*DIN + d)*DSTN + sq*4;
    float4 Pv = *(const float4*)(P_ws + pb);
    float4 Hv = *(const float4*)(hend_ws + pb);
    h0 = fmaf(Pv.x, h0, Hv.x); h1 = fmaf(Pv.y, h1, Hv.y);
    h2 = fmaf(Pv.z, h2, Hv.z); h3 = fmaf(Pv.w, h3, Hv.w);
  }
  float Dp = (dir ? D_b : D_f)[d];
  size_t base = ((size_t)dir*NSEQ + n)*LN + g*CLEN;
  const float* dtp = dt_ws + base*DIN + d;
  const float* xsp = xs_ws + base*DIN + d;
  const float* zsp = zs_ws + base*DIN + d;
  const float4* Bp = (const float4*)(B_ws + base*DSTN) + sq;
  const float4* Cp = (const float4*)(C_ws + base*DSTN) + sq;
  float* yp = y_ws + base*DIN + d;
  #pragma unroll 4
  for (int i = 0; i < CLEN; ++i) {
    float dtv = dtp[i*DIN];
    float xv  = xsp[i*DIN];
    float4 Bv = Bp[i*4];
    float4 Cv = Cp[i*4];
    float dtx = dtv*xv;
    float a0 = __expf(dtv*A0), a1 = __expf(dtv*A1);
    float a2 = __expf(dtv*A2), a3 = __expf(dtv*A3);
    h0 = fmaf(a0, h0, dtx*Bv.x); h1 = fmaf(a1, h1, dtx*Bv.y);
    h2 = fmaf(a2, h2, dtx*Bv.z); h3 = fmaf(a3, h3, dtx*Bv.w);
    float p = h0*Cv.x + h1*Cv.y + h2*Cv.z + h3*Cv.w;
    p += __shfl_xor(p, 1);
    p += __shfl_xor(p, 2);
    if (sq == 0) {
      float zv = zsp[i*DIN];
      yp[i*DIN] = (p + Dp*xv)*zv;
    }
  }
}

// ---------------- K45: dir-combine + 64->32 proj + 32->256 proj + 4x4 upsample ----------------
__global__ __launch_bounds__(256) void bm3d_k45_out(
    const float* __restrict__ y_ws, const float* __restrict__ owT,
    const float* __restrict__ w_out, float* __restrict__ out) {
  __shared__ float wo[CC*CRD];      // 32KB
  __shared__ float ow2[2*DIN*CRD];  // 16KB  [dir][dd][r]
  __shared__ float yfs[32*65];      // padded (8.3KB)
  __shared__ float ybs[32*65];
  __shared__ float ymt[32*33];      // padded (4.2KB)
  int b = blockIdx.x;               // 512 = 16 d * 32 hs
  int d = b >> 5, hs = b & 31;
  int t = threadIdx.x;
  for (int i = t; i < CC*CRD; i += 256) wo[i] = w_out[i];
  for (int i = t; i < 2*DIN*CRD; i += 256) ow2[i] = owT[i];
  // load y tiles: 32 tokens x 64 dd, fwd + bwd(reversed)
  for (int i = t; i < 32*DIN; i += 256) {
    int q = i >> 6, dd = i & 63;
    int l = hs*32 + q;
    yfs[q*65 + dd] = y_ws[((size_t)d*LN + l)*DIN + dd];
    ybs[q*65 + dd] = y_ws[((size_t)(NSEQ + d)*LN + (LN-1-l))*DIN + dd];
  }
  __syncthreads();
  // combine: ymt[q][r] = 0.5*sum_dd (yf*owf + yb*owb)
  {
    int q = t >> 3, rb = (t & 7) * 4;
    const float* yfr = yfs + q*65;
    const float* ybr = ybs + q*65;
    float acc0=0.f, acc1=0.f, acc2=0.f, acc3=0.f;
    #pragma unroll 8
    for (int dd = 0; dd < DIN; ++dd) {
      float yf = yfr[dd], yb = ybr[dd];
      const float* wf = ow2 + dd*CRD + rb;
      const float* wb = ow2 + (DIN+dd)*CRD + rb;
      acc0 = fmaf(yf, wf[0], fmaf(yb, wb[0], acc0));
      acc1 = fmaf(yf, wf[1], fmaf(yb, wb[1], acc1));
      acc2 = fmaf(yf, wf[2], fmaf(yb, wb[2], acc2));
      acc3 = fmaf(yf, wf[3], fmaf(yb, wb[3], acc3));
    }
    ymt[q*33 + rb+0] = 0.5f*acc0; ymt[q*33 + rb+1] = 0.5f*acc1;
    ymt[q*33 + rb+2] = 0.5f*acc2; ymt[q*33 + rb+3] = 0.5f*acc3;
  }
  __syncthreads();
  // projection 32->256 + 4x4 upsample, coalesced float4 rows
  {
    int q = t & 31, cg = t >> 5;
    const float* fr = ymt + q*33;
    for (int ci = 0; ci < 32; ++ci) {
      int c = cg*32 + ci;
      const float* wr = wo + c*CRD;
      float acc = 0.f;
      #pragma unroll 8
      for (int r = 0; r < 32; ++r) acc = fmaf(wr[r], fr[r], acc);
      float4 v = make_float4(acc, acc, acc, acc);
      size_t rowbase = (((size_t)c*DD + d)*HH + 4*hs)*WWD + 4*q;
      *(float4*)(out + rowbase)           = v;
      *(float4*)(out + rowbase +   WWD)   = v;
      *(float4*)(out + rowbase + 2*WWD)   = v;
      *(float4*)(out + rowbase + 3*WWD)   = v;
    }
  }
}

extern "C" void kernel_launch(void* const* d_in, const int* in_sizes, int n_in,
                              void* d_out, int out_size, void* d_ws, size_t ws_size,
                              hipStream_t stream) {
  const float* x      = (const float*)d_in[0];
  const float* w_in   = (const float*)d_in[1];
  const float* w_out  = (const float*)d_in[2];
  const float* ln_w   = (const float*)d_in[3];
  const float* ln_b   = (const float*)d_in[4];
  const float* mf_in_w   = (const float*)d_in[5];
  const float* mf_conv_w = (const float*)d_in[6];
  const float* mf_conv_b = (const float*)d_in[7];
  const float* mf_xproj  = (const float*)d_in[8];
  const float* mf_dt_w   = (const float*)d_in[9];
  const float* mf_dt_b   = (const float*)d_in[10];
  const float* mf_A_log  = (const float*)d_in[11];
  const float* mf_D      = (const float*)d_in[12];
  const float* mf_out_w  = (const float*)d_in[13];
  const float* mb_in_w   = (const float*)d_in[14];
  const float* mb_conv_w = (const float*)d_in[15];
  const float* mb_conv_b = (const float*)d_in[16];
  const float* mb_xproj  = (const float*)d_in[17];
  const float* mb_dt_w   = (const float*)d_in[18];
  const float* mb_dt_b   = (const float*)d_in[19];
  const float* mb_A_log  = (const float*)d_in[20];
  const float* mb_D      = (const float*)d_in[21];
  const float* mb_out_w  = (const float*)d_in[22];

  float* ws   = (float*)d_ws;
  float* tokn = ws + OFF_TOKN;
  float* xs   = ws + OFF_XS;
  float* dtw_ = ws + OFF_DT;
  float* zs   = ws + OFF_ZS;
  float* Bw   = ws + OFF_B;
  float* Cw   = ws + OFF_C;
  float* yw   = ws + OFF_Y;
  float* Pw   = ws + OFF_P;
  float* He   = ws + OFF_HE;
  float* inwT = ws + OFF_INWT;
  float* xpT  = ws + OFF_XPT;
  float* owT  = ws + OFF_OWT;
  float* An   = ws + OFF_AN;
  float* winT = ws + OFF_WINT;

  bm3d_k0_prep<<<32, 256, 0, stream>>>(mf_in_w, mb_in_w, mf_xproj, mb_xproj,
                                  mf_out_w, mb_out_w, mf_A_log, mb_A_log,
                                  w_in, inwT, xpT, owT, An, winT);
  bm3d_k1_token_ln<<<512, 256, 0, stream>>>(x, winT, ln_w, ln_b, tokn);
  bm3d_k2_prescan_chunk<<<512, 256, 0, stream>>>(tokn, inwT, xpT,
                                      mf_conv_w, mf_conv_b, mf_dt_w, mf_dt_b,
                                      mb_conv_w, mb_conv_b, mb_dt_w, mb_dt_b,
                                      An, xs, dtw_, zs, Bw, Cw, Pw, He);
  bm3d_k3_scan<<<512, 256, 0, stream>>>(dtw_, xs, Bw, Cw, zs, An, Pw, He,
                                    mf_D, mb_D, yw);
  bm3d_k45_out<<<512, 256, 0, stream>>>(yw, owT, w_out, (float*)d_out);
}

// Round 4
// 194.901 us; speedup vs baseline: 1.0850x; 1.0055x over previous
//
#include <hip/hip_runtime.h>
#include <math.h>

#define CC   256
#define DD   16
#define HH   128
#define WWD  128
#define CRD  32
#define DSTN 16
#define DIN  64
#define LN   1024
#define NSEQ 16
#define GCH  16
#define CLEN 64

typedef float f32x4 __attribute__((ext_vector_type(4)));

// ---------------- workspace layout (floats) ----------------
constexpr size_t NTOK = (size_t)NSEQ * LN;                          // 16384 tokens
constexpr size_t OFF_TOKN = 0;                                      // [16][1024][32]
constexpr size_t OFF_YM   = OFF_TOKN + NTOK*CRD;                    // [16][1024][32]
constexpr size_t OFF_P    = OFF_YM   + NTOK*CRD;                    // [2][16][16][64][16]
constexpr size_t OFF_HE   = OFF_P    + 2*(size_t)NSEQ*GCH*DIN*DSTN;
constexpr size_t OFF_INWT = OFF_HE   + 2*(size_t)NSEQ*GCH*DIN*DSTN; // [2][32][128]
constexpr size_t OFF_XPT  = OFF_INWT + 2*(size_t)CRD*128;           // [2][64][34]
constexpr size_t OFF_OW2  = OFF_XPT  + 2*(size_t)DIN*34;            // [2][64][32]
constexpr size_t OFF_AN   = OFF_OW2  + 2*(size_t)DIN*CRD;           // [2][64][16]

__device__ __forceinline__ float siluf(float x) { return x / (1.0f + __expf(-x)); }
__device__ __forceinline__ float softplusf(float z) {
  return (z > 20.f) ? z : log1pf(__expf(z));
}

// ---------------- K1: tokenize (256->32 proj + LN) + prep tables ----------------
__global__ __launch_bounds__(256) void bm3d_k1_token_ln(
    const float* __restrict__ x, const float* __restrict__ w_in,
    const float* __restrict__ ln_w, const float* __restrict__ ln_b,
    const float* __restrict__ inw_f, const float* __restrict__ inw_b,
    const float* __restrict__ xp_f,  const float* __restrict__ xp_b,
    const float* __restrict__ ow_f,  const float* __restrict__ ow_b,
    const float* __restrict__ al_f,  const float* __restrict__ al_b,
    float* __restrict__ tokn,
    float* __restrict__ inwT, float* __restrict__ xpT,
    float* __restrict__ ow2, float* __restrict__ An) {
  __shared__ float xv[CC*CRD];      // [c][ws] 32KB
  __shared__ float wT[CC*33];       // [c][r] padded 33KB
  __shared__ float zt[CRD][33];     // [r][ws]
  __shared__ float mu_s[32], rs_s[32];
  int b = blockIdx.x;               // 512 = 16 d * 32 hs
  int d = b >> 5, hs = b & 31;
  int t = threadIdx.x;

  // prep tables (blocks 0..31 only; consumed by K2/K3)
  if (b < 32) {
    int gt = b*256 + t;
    for (int i = gt; i < 2*CRD*128; i += 8192) {      // inwT[dir][dd][e]
      int dir = i >> 12, rem = i & 4095, dd = rem >> 7, e = rem & 127;
      inwT[i] = (dir ? inw_b : inw_f)[e*CRD + dd];
    }
    for (int i = gt; i < 2*DIN*34; i += 8192) {       // xpT[dir][dd][e]
      int dir = i / (DIN*34), rem = i - dir*(DIN*34);
      int dd = rem / 34, e = rem - dd*34;
      xpT[i] = (dir ? xp_b : xp_f)[e*DIN + dd];
    }
    for (int i = gt; i < 2*DIN*CRD; i += 8192) {      // ow2[dir][dd][r]
      int dir = i >> 11, rem = i & 2047, dd = rem >> 5, r = rem & 31;
      ow2[i] = (dir ? ow_b : ow_f)[r*DIN + dd];
    }
    for (int i = gt; i < 2*DIN*DSTN; i += 8192) {     // An = -exp(A_log)
      int dir = i >> 10, rem = i & 1023;
      An[i] = -expf((dir ? al_b : al_f)[rem]);
    }
  }

  // in-LDS transpose of w_in: wT[c][r] = w_in[r][c]
  for (int it = 0; it < 8; ++it) {
    int f4 = t + it*256;            // 2048 float4
    float4 v = ((const float4*)w_in)[f4];
    int f = f4*4;
    int r = f >> 8, c = f & 255;
    wT[(c+0)*33 + r] = v.x; wT[(c+1)*33 + r] = v.y;
    wT[(c+2)*33 + r] = v.z; wT[(c+3)*33 + r] = v.w;
  }
  // load x[c, d, 4hs, 4ws]: fetch float4 row chunk, keep .x (line fetched anyway)
  {
    int wsx = t & 31, cg = t >> 5;
    const float4* xbase = (const float4*)(x + ((size_t)d*HH + 4*hs)*WWD) + wsx;
    #pragma unroll 8
    for (int i = 0; i < 32; ++i) {
      int c = cg*32 + i;
      xv[c*CRD + wsx] = xbase[(size_t)c*(DD*HH*WWD/4)].x;
    }
  }
  __syncthreads();
  // z[r][ws] = sum_c wT[c][r] * xv[c][ws]
  {
    int r = t & 31, wq = t >> 5;
    float a0=0.f,a1=0.f,a2=0.f,a3=0.f;
    #pragma unroll 8
    for (int c = 0; c < CC; ++c) {
      float w = wT[c*33 + r];
      float4 xq = *(const float4*)(xv + c*CRD + wq*4);
      a0 = fmaf(w, xq.x, a0); a1 = fmaf(w, xq.y, a1);
      a2 = fmaf(w, xq.z, a2); a3 = fmaf(w, xq.w, a3);
    }
    zt[r][wq*4+0] = a0; zt[r][wq*4+1] = a1;
    zt[r][wq*4+2] = a2; zt[r][wq*4+3] = a3;
  }
  __syncthreads();
  if (t < 32) {
    float mu = 0.f;
    for (int r = 0; r < 32; ++r) mu += zt[r][t];
    mu *= (1.0f/32.0f);
    float var = 0.f;
    for (int r = 0; r < 32; ++r) { float dl = zt[r][t]-mu; var = fmaf(dl, dl, var); }
    var *= (1.0f/32.0f);
    mu_s[t] = mu; rs_s[t] = 1.0f/sqrtf(var + 1e-5f);
  }
  __syncthreads();
  float* outp = tokn + ((size_t)d*LN + hs*32)*CRD;
  for (int it = t; it < 1024; it += 256) {
    int w2 = it >> 5, r2 = it & 31;
    outp[it] = (zt[r2][w2]-mu_s[w2])*rs_s[w2]*ln_w[r2] + ln_b[r2];
  }
}

// ---------------- K2: chunk transitions only (P, h_end from h=0) ----------------
__global__ __launch_bounds__(256) void bm3d_k2_chunk(
    const float* __restrict__ tokn, const float* __restrict__ ws_inwT,
    const float* __restrict__ ws_xpT,
    const float* __restrict__ cw_f, const float* __restrict__ cb_f,
    const float* __restrict__ dtw_f, const float* __restrict__ dtb_f,
    const float* __restrict__ cw_b, const float* __restrict__ cb_b,
    const float* __restrict__ dtw_b, const float* __restrict__ dtb_b,
    const float* __restrict__ An,
    float* __restrict__ P_ws, float* __restrict__ hend_ws) {
  __shared__ float tk[67*CRD];      // 8.6KB
  __shared__ float xr[67*DIN];      // 17.2KB
  __shared__ float xsld[64*DIN];    // 16KB
  __shared__ float dbc[64*18];      // dt(2) + B(16) only, 4.6KB
  __shared__ float dts[64*DIN];     // 16KB
  int b = blockIdx.x;               // 512 = 2 dir * 16 n * 16 g
  int dir = b >> 8, n = (b >> 4) & 15, g = b & 15;
  int l0 = g*CLEN;
  int t = threadIdx.x;
  const float* inwT = ws_inwT + (size_t)dir*CRD*128;
  const float* xpT  = ws_xpT  + (size_t)dir*DIN*34;
  const float* cw  = dir ? cw_b  : cw_f;
  const float* cb  = dir ? cb_b  : cb_f;
  const float* dtw = dir ? dtw_b : dtw_f;
  const float* dtb = dir ? dtb_b : dtb_f;

  for (int i = t; i < 67*CRD; i += 256) {
    int row = i >> 5, col = i & 31;
    int lb = l0 - 3 + row;
    float v = 0.f;
    if (lb >= 0) {
      int lo = dir ? (LN-1-lb) : lb;
      v = tokn[((size_t)n*LN + lo)*CRD + col];
    }
    tk[i] = v;
  }
  __syncthreads();
  for (int i = t; i < 67*DIN; i += 256) {       // A: x pre-conv
    int row = i >> 6, e = i & 63;
    float acc = 0.f;
    const float* tkr = tk + row*CRD;
    #pragma unroll 8
    for (int dd = 0; dd < CRD; ++dd) acc = fmaf(tkr[dd], inwT[dd*128 + e], acc);
    xr[i] = acc;
  }
  __syncthreads();
  for (int i = t; i < 64*DIN; i += 256) {       // C: conv4 + silu
    int r = i >> 6, dd = i & 63;
    float acc = cb[dd];
    #pragma unroll
    for (int k = 0; k < 4; ++k) acc = fmaf(cw[dd*4+k], xr[(r+k)*DIN + dd], acc);
    xsld[i] = siluf(acc);
  }
  __syncthreads();
  for (int i = t; i < 64*18; i += 256) {        // D1: dt-pre + B
    int r = i / 18, e = i - r*18;
    float acc = 0.f;
    const float* xsr = xsld + r*DIN;
    #pragma unroll 8
    for (int dd = 0; dd < DIN; ++dd) acc = fmaf(xsr[dd], xpT[dd*34 + e], acc);
    dbc[i] = acc;
  }
  __syncthreads();
  for (int i = t; i < 64*DIN; i += 256) {       // D2: softplus dt
    int r = i >> 6, dd = i & 63;
    float z = fmaf(dbc[r*18+0], dtw[dd*2+0], fmaf(dbc[r*18+1], dtw[dd*2+1], dtb[dd]));
    dts[i] = softplusf(z);
  }
  __syncthreads();
  {
    int dd = t >> 2, sq = t & 3;
    const float* Ap = An + ((size_t)dir*DIN + dd)*DSTN + sq*4;
    float A0 = Ap[0], A1 = Ap[1], A2 = Ap[2], A3 = Ap[3];
    float h0=0.f,h1=0.f,h2=0.f,h3=0.f, P0=1.f,P1=1.f,P2=1.f,P3=1.f;
    #pragma unroll 4
    for (int i = 0; i < CLEN; ++i) {
      float dtv = dts[i*DIN + dd];
      float xv  = xsld[i*DIN + dd];
      float b0 = dbc[i*18 + 2 + sq*4 + 0];
      float b1 = dbc[i*18 + 2 + sq*4 + 1];
      float b2 = dbc[i*18 + 2 + sq*4 + 2];
      float b3 = dbc[i*18 + 2 + sq*4 + 3];
      float dtx = dtv*xv;
      float a0 = __expf(dtv*A0), a1 = __expf(dtv*A1);
      float a2 = __expf(dtv*A2), a3 = __expf(dtv*A3);
      P0 *= a0; P1 *= a1; P2 *= a2; P3 *= a3;
      h0 = fmaf(a0, h0, dtx*b0); h1 = fmaf(a1, h1, dtx*b1);
      h2 = fmaf(a2, h2, dtx*b2); h3 = fmaf(a3, h3, dtx*b3);
    }
    size_t pbase = ((((size_t)dir*NSEQ + n)*GCH + g)*DIN + dd)*DSTN + sq*4;
    *(float4*)(P_ws + pbase)    = make_float4(P0,P1,P2,P3);
    *(float4*)(hend_ws + pbase) = make_float4(h0,h1,h2,h3);
  }
}

// ---------------- K3: both-dir full scan + gate + combine + 64->32 proj ----------------
// LDS regions (floats):
//   zbuf  [0,8192)        xsld [8192,16384)      dbc [16384,20736) stride34
//   tkow  [20736,25024)   (tk 2x67x32, later ow2 2x64x32)
//   xrys  [25024,33600)   (xr 2x67x64, later ys 2x64x65)
__global__ __launch_bounds__(512) void bm3d_k3_scan(
    const float* __restrict__ tokn, const float* __restrict__ ws_inwT,
    const float* __restrict__ ws_xpT, const float* __restrict__ ws_ow2,
    const float* __restrict__ cw_f, const float* __restrict__ cb_f,
    const float* __restrict__ dtw_f, const float* __restrict__ dtb_f,
    const float* __restrict__ cw_b, const float* __restrict__ cb_b,
    const float* __restrict__ dtw_b, const float* __restrict__ dtb_b,
    const float* __restrict__ An,
    const float* __restrict__ P_ws, const float* __restrict__ hend_ws,
    const float* __restrict__ D_f, const float* __restrict__ D_b,
    float* __restrict__ ym) {
  __shared__ float lds[33600];      // 131.25 KB
  float* zbuf = lds;
  float* xsld = lds + 8192;
  float* dbc  = lds + 16384;
  float* tkow = lds + 20736;
  float* xrys = lds + 25024;
  int b = blockIdx.x;               // 256 = 16 n * 16 g
  int n = b >> 4, g = b & 15;
  int t = threadIdx.x;
  int gd_of[2] = { g, 15 - g };     // scan-order chunk per dir (same orig tokens)

  // load tk for both dirs
  for (int i = t; i < 2*67*CRD; i += 512) {
    int dir = i / 2144, rem = i - dir*2144;
    int row = rem >> 5, col = rem & 31;
    int lb = gd_of[dir]*CLEN - 3 + row;
    float v = 0.f;
    if (lb >= 0) {
      int lo = dir ? (LN-1-lb) : lb;
      v = tokn[((size_t)n*LN + lo)*CRD + col];
    }
    tkow[dir*2144 + row*32 + col] = v;
  }
  __syncthreads();
  // phase A: xr  (x pre-conv, 67 rows)
  for (int i = t; i < 2*67*DIN; i += 512) {
    int dir = i / 4288, rem = i - dir*4288;
    int row = rem >> 6, e = rem & 63;
    const float* tkr = tkow + dir*2144 + row*32;
    const float* inwT = ws_inwT + (size_t)dir*CRD*128;
    float acc = 0.f;
    #pragma unroll 8
    for (int dd = 0; dd < CRD; ++dd) acc = fmaf(tkr[dd], inwT[dd*128 + e], acc);
    xrys[dir*4288 + row*64 + e] = acc;
  }
  // phase B: z-gate -> silu -> zbuf
  for (int i = t; i < 2*64*DIN; i += 512) {
    int dir = i >> 12, rem = i & 4095;
    int row = rem >> 6, e = rem & 63;
    const float* tkr = tkow + dir*2144 + (row+3)*32;
    const float* inwT = ws_inwT + (size_t)dir*CRD*128;
    float acc = 0.f;
    #pragma unroll 8
    for (int dd = 0; dd < CRD; ++dd) acc = fmaf(tkr[dd], inwT[dd*128 + 64 + e], acc);
    zbuf[i] = siluf(acc);
  }
  __syncthreads();                  // tk dead; ow2 overlays it
  for (int i = t; i < 2*DIN*CRD; i += 512) tkow[i] = ws_ow2[i];
  // phase C: conv4 + silu
  for (int i = t; i < 2*64*DIN; i += 512) {
    int dir = i >> 12, rem = i & 4095;
    int r = rem >> 6, dd = rem & 63;
    const float* cw = dir ? cw_b : cw_f;
    const float* cb = dir ? cb_b : cb_f;
    float acc = cb[dd];
    const float* xrb = xrys + dir*4288;
    #pragma unroll
    for (int k = 0; k < 4; ++k) acc = fmaf(cw[dd*4+k], xrb[(r+k)*DIN + dd], acc);
    xsld[i] = siluf(acc);
  }
  __syncthreads();                  // xr dead; ys overlays it
  // phase D1: dbc (dt-pre 0..1, B 2..17, C 18..33)
  for (int i = t; i < 2*64*34; i += 512) {
    int dir = i / 2176, rem = i - dir*2176;
    int r = rem / 34, e = rem - r*34;
    const float* xsr = xsld + dir*4096 + r*DIN;
    const float* xpT = ws_xpT + (size_t)dir*DIN*34;
    float acc = 0.f;
    #pragma unroll 8
    for (int dd = 0; dd < DIN; ++dd) acc = fmaf(xsr[dd], xpT[dd*34 + e], acc);
    dbc[dir*2176 + r*34 + e] = acc;
  }
  __syncthreads();
  // scan: thread = (dir, d, sq)
  {
    int dir = t >> 8, dd = (t >> 2) & 63, sq = t & 3;
    int gd = gd_of[dir];
    const float* Ap = An + ((size_t)dir*DIN + dd)*DSTN + sq*4;
    float A0 = Ap[0], A1 = Ap[1], A2 = Ap[2], A3 = Ap[3];
    const float* dtw = dir ? dtw_b : dtw_f;
    const float* dtb = dir ? dtb_b : dtb_f;
    float w0 = dtw[dd*2+0], w1 = dtw[dd*2+1], bb = dtb[dd];
    float Dp = (dir ? D_b : D_f)[dd];
    float h0=0.f,h1=0.f,h2=0.f,h3=0.f;
    for (int gp = 0; gp < gd; ++gp) {
      size_t pb = ((((size_t)dir*NSEQ + n)*GCH + gp)*DIN + dd)*DSTN + sq*4;
      float4 Pv = *(const float4*)(P_ws + pb);
      float4 Hv = *(const float4*)(hend_ws + pb);
      h0 = fmaf(Pv.x, h0, Hv.x); h1 = fmaf(Pv.y, h1, Hv.y);
      h2 = fmaf(Pv.z, h2, Hv.z); h3 = fmaf(Pv.w, h3, Hv.w);
    }
    const float* dbcd = dbc + dir*2176;
    const float* xsd  = xsld + dir*4096;
    const float* zbd  = zbuf + dir*4096;
    float* ysd = xrys + dir*4160;
    #pragma unroll 4
    for (int i = 0; i < CLEN; ++i) {
      float p0 = dbcd[i*34+0], p1 = dbcd[i*34+1];
      float dtv = softplusf(fmaf(p0, w0, fmaf(p1, w1, bb)));
      float xv  = xsd[i*DIN + dd];
      float b0 = dbcd[i*34 + 2 + sq*4 + 0];
      float b1 = dbcd[i*34 + 2 + sq*4 + 1];
      float b2 = dbcd[i*34 + 2 + sq*4 + 2];
      float b3 = dbcd[i*34 + 2 + sq*4 + 3];
      float c0 = dbcd[i*34 + 18 + sq*4 + 0];
      float c1 = dbcd[i*34 + 18 + sq*4 + 1];
      float c2 = dbcd[i*34 + 18 + sq*4 + 2];
      float c3 = dbcd[i*34 + 18 + sq*4 + 3];
      float dtx = dtv*xv;
      float a0 = __expf(dtv*A0), a1 = __expf(dtv*A1);
      float a2 = __expf(dtv*A2), a3 = __expf(dtv*A3);
      h0 = fmaf(a0, h0, dtx*b0); h1 = fmaf(a1, h1, dtx*b1);
      h2 = fmaf(a2, h2, dtx*b2); h3 = fmaf(a3, h3, dtx*b3);
      float p = h0*c0 + h1*c1 + h2*c2 + h3*c3;
      p += __shfl_xor(p, 1);
      p += __shfl_xor(p, 2);
      if (sq == 0) {
        int li = dir ? (63 - i) : i;
        ysd[li*65 + dd] = (p + Dp*xv)*zbd[i*DIN + dd];
      }
    }
  }
  __syncthreads();
  // combine + 64->32 projection: ym[token][r]
  {
    int q = t >> 3, rb = (t & 7) * 4;
    const float* ys0 = xrys + q*65;
    const float* ys1 = xrys + 4160 + q*65;
    const float* wf = tkow;          // ow2[0][dd][r]
    const float* wb = tkow + 2048;   // ow2[1][dd][r]
    float a0=0.f,a1=0.f,a2=0.f,a3=0.f;
    #pragma unroll 8
    for (int dd = 0; dd < DIN; ++dd) {
      float yf = ys0[dd], yb = ys1[dd];
      const float* wfr = wf + dd*CRD + rb;
      const float* wbr = wb + dd*CRD + rb;
      a0 = fmaf(yf, wfr[0], fmaf(yb, wbr[0], a0));
      a1 = fmaf(yf, wfr[1], fmaf(yb, wbr[1], a1));
      a2 = fmaf(yf, wfr[2], fmaf(yb, wbr[2], a2));
      a3 = fmaf(yf, wfr[3], fmaf(yb, wbr[3], a3));
    }
    float4 v = make_float4(0.5f*a0, 0.5f*a1, 0.5f*a2, 0.5f*a3);
    *(float4*)(ym + ((size_t)n*LN + g*CLEN + q)*CRD + rb) = v;
  }
}

// ---------------- K45: 32->256 projection + 4x4 upsample (write-bound) ----------------
__global__ __launch_bounds__(256) void bm3d_k45_out(
    const float* __restrict__ ym, const float* __restrict__ w_out,
    float* __restrict__ out) {
  __shared__ float wo[CC*CRD];      // 32KB
  __shared__ float ymt[32*33];      // padded
  int b = blockIdx.x;               // 512 = 16 d * 32 hs
  int d = b >> 5, hs = b & 31;
  int t = threadIdx.x;
  for (int i = t; i < CC*CRD; i += 256) wo[i] = w_out[i];
  const float* fb = ym + ((size_t)d*LN + hs*32)*CRD;
  for (int i = t; i < 1024; i += 256) {
    int wq = i >> 5, r = i & 31;
    ymt[wq*33 + r] = fb[i];
  }
  __syncthreads();
  int q = t & 31, cg = t >> 5;
  const float* fr = ymt + q*33;
  for (int ci = 0; ci < 32; ++ci) {
    int c = cg*32 + ci;
    const float* wr = wo + c*CRD;
    float acc = 0.f;
    #pragma unroll 8
    for (int r = 0; r < 32; ++r) acc = fmaf(wr[r], fr[r], acc);
    f32x4 v = { acc, acc, acc, acc };
    size_t rowbase = (((size_t)c*DD + d)*HH + 4*hs)*WWD + 4*q;
    __builtin_nontemporal_store(v, (f32x4*)(out + rowbase));
    __builtin_nontemporal_store(v, (f32x4*)(out + rowbase +   WWD));
    __builtin_nontemporal_store(v, (f32x4*)(out + rowbase + 2*WWD));
    __builtin_nontemporal_store(v, (f32x4*)(out + rowbase + 3*WWD));
  }
}

extern "C" void kernel_launch(void* const* d_in, const int* in_sizes, int n_in,
                              void* d_out, int out_size, void* d_ws, size_t ws_size,
                              hipStream_t stream) {
  const float* x      = (const float*)d_in[0];
  const float* w_in   = (const float*)d_in[1];
  const float* w_out  = (const float*)d_in[2];
  const float* ln_w   = (const float*)d_in[3];
  const float* ln_b   = (const float*)d_in[4];
  const float* mf_in_w   = (const float*)d_in[5];
  const float* mf_conv_w = (const float*)d_in[6];
  const float* mf_conv_b = (const float*)d_in[7];
  const float* mf_xproj  = (const float*)d_in[8];
  const float* mf_dt_w   = (const float*)d_in[9];
  const float* mf_dt_b   = (const float*)d_in[10];
  const float* mf_A_log  = (const float*)d_in[11];
  const float* mf_D      = (const float*)d_in[12];
  const float* mf_out_w  = (const float*)d_in[13];
  const float* mb_in_w   = (const float*)d_in[14];
  const float* mb_conv_w = (const float*)d_in[15];
  const float* mb_conv_b = (const float*)d_in[16];
  const float* mb_xproj  = (const float*)d_in[17];
  const float* mb_dt_w   = (const float*)d_in[18];
  const float* mb_dt_b   = (const float*)d_in[19];
  const float* mb_A_log  = (const float*)d_in[20];
  const float* mb_D      = (const float*)d_in[21];
  const float* mb_out_w  = (const float*)d_in[22];

  float* ws   = (float*)d_ws;
  float* tokn = ws + OFF_TOKN;
  float* ym   = ws + OFF_YM;
  float* Pw   = ws + OFF_P;
  float* He   = ws + OFF_HE;
  float* inwT = ws + OFF_INWT;
  float* xpT  = ws + OFF_XPT;
  float* ow2  = ws + OFF_OW2;
  float* An   = ws + OFF_AN;

  bm3d_k1_token_ln<<<512, 256, 0, stream>>>(x, w_in, ln_w, ln_b,
                                            mf_in_w, mb_in_w, mf_xproj, mb_xproj,
                                            mf_out_w, mb_out_w, mf_A_log, mb_A_log,
                                            tokn, inwT, xpT, ow2, An);
  bm3d_k2_chunk<<<512, 256, 0, stream>>>(tokn, inwT, xpT,
                                         mf_conv_w, mf_conv_b, mf_dt_w, mf_dt_b,
                                         mb_conv_w, mb_conv_b, mb_dt_w, mb_dt_b,
                                         An, Pw, He);
  bm3d_k3_scan<<<256, 512, 0, stream>>>(tokn, inwT, xpT, ow2,
                                        mf_conv_w, mf_conv_b, mf_dt_w, mf_dt_b,
                                        mb_conv_w, mb_conv_b, mb_dt_w, mb_dt_b,
                                        An, Pw, He, mf_D, mb_D, ym);
  bm3d_k45_out<<<512, 256, 0, stream>>>(ym, w_out, (float*)d_out);
}

// Round 5
// 181.246 us; speedup vs baseline: 1.1667x; 1.0753x over previous
//
#include <hip/hip_runtime.h>
#include <math.h>

#define CC   256
#define DD   16
#define HH   128
#define WWD  128
#define CRD  32
#define DSTN 16
#define DIN  64
#define LN   1024
#define NSEQ 16
#define GCH  16
#define CLEN 64

typedef float f32x4 __attribute__((ext_vector_type(4)));

// ---------------- workspace layout (floats) ----------------
constexpr size_t NTOK = (size_t)NSEQ * LN;                          // 16384 tokens
constexpr size_t OFF_TOKN = 0;                                      // [16][1024][32]
constexpr size_t OFF_YM   = OFF_TOKN + NTOK*CRD;                    // [16][1024][32]
constexpr size_t OFF_P    = OFF_YM   + NTOK*CRD;                    // [2][16][16][64][16]
constexpr size_t OFF_HE   = OFF_P    + 2*NTOK*DIN;                  // (= 2*16*16*64*16)
constexpr size_t OFF_XS   = OFF_HE   + 2*NTOK*DIN;                  // [2][16][1024][64]
constexpr size_t OFF_ZS   = OFF_XS   + 2*NTOK*DIN;                  // [2][16][1024][64]
constexpr size_t OFF_REC  = OFF_ZS   + 2*NTOK*DIN;                  // [2][16][1024][36]
constexpr size_t OFF_INWT = OFF_REC  + 2*NTOK*36;                   // [2][32][128]
constexpr size_t OFF_XPT  = OFF_INWT + 2*(size_t)CRD*128;           // [2][64][34]
constexpr size_t OFF_OW2  = OFF_XPT  + 2*(size_t)DIN*34;            // [2][64][32]
constexpr size_t OFF_AN   = OFF_OW2  + 2*(size_t)DIN*CRD;           // [2][64][16]

__device__ __forceinline__ float siluf(float x) { return x / (1.0f + __expf(-x)); }
__device__ __forceinline__ float softplusf(float z) {
  return (z > 20.f) ? z : log1pf(__expf(z));
}

// ---------------- K1: tokenize (256->32 proj + LN) + prep tables ----------------
__global__ __launch_bounds__(256) void bm3d_k1_token_ln(
    const float* __restrict__ x, const float* __restrict__ w_in,
    const float* __restrict__ ln_w, const float* __restrict__ ln_b,
    const float* __restrict__ inw_f, const float* __restrict__ inw_b,
    const float* __restrict__ xp_f,  const float* __restrict__ xp_b,
    const float* __restrict__ ow_f,  const float* __restrict__ ow_b,
    const float* __restrict__ al_f,  const float* __restrict__ al_b,
    float* __restrict__ tokn,
    float* __restrict__ inwT, float* __restrict__ xpT,
    float* __restrict__ ow2, float* __restrict__ An) {
  __shared__ float xv[CC*CRD];      // [c][ws] 32KB
  __shared__ float wT[CC*33];       // [c][r] padded 33KB
  __shared__ float zt[CRD][33];     // [r][ws]
  __shared__ float mu_s[32], rs_s[32];
  int b = blockIdx.x;               // 512 = 16 d * 32 hs
  int d = b >> 5, hs = b & 31;
  int t = threadIdx.x;

  // prep tables (blocks 0..31 only; consumed by K2/K3)
  if (b < 32) {
    int gt = b*256 + t;
    for (int i = gt; i < 2*CRD*128; i += 8192) {      // inwT[dir][dd][e]
      int dir = i >> 12, rem = i & 4095, dd = rem >> 7, e = rem & 127;
      inwT[i] = (dir ? inw_b : inw_f)[e*CRD + dd];
    }
    for (int i = gt; i < 2*DIN*34; i += 8192) {       // xpT[dir][dd][e]
      int dir = i / (DIN*34), rem = i - dir*(DIN*34);
      int dd = rem / 34, e = rem - dd*34;
      xpT[i] = (dir ? xp_b : xp_f)[e*DIN + dd];
    }
    for (int i = gt; i < 2*DIN*CRD; i += 8192) {      // ow2[dir][dd][r]
      int dir = i >> 11, rem = i & 2047, dd = rem >> 5, r = rem & 31;
      ow2[i] = (dir ? ow_b : ow_f)[r*DIN + dd];
    }
    for (int i = gt; i < 2*DIN*DSTN; i += 8192) {     // An = -exp(A_log)
      int dir = i >> 10, rem = i & 1023;
      An[i] = -expf((dir ? al_b : al_f)[rem]);
    }
  }

  // in-LDS transpose of w_in: wT[c][r] = w_in[r][c]
  for (int it = 0; it < 8; ++it) {
    int f4 = t + it*256;            // 2048 float4
    float4 v = ((const float4*)w_in)[f4];
    int f = f4*4;
    int r = f >> 8, c = f & 255;
    wT[(c+0)*33 + r] = v.x; wT[(c+1)*33 + r] = v.y;
    wT[(c+2)*33 + r] = v.z; wT[(c+3)*33 + r] = v.w;
  }
  // load x[c, d, 4hs, 4ws]: fetch float4 row chunk, keep .x (line fetched anyway)
  {
    int wsx = t & 31, cg = t >> 5;
    const float4* xbase = (const float4*)(x + ((size_t)d*HH + 4*hs)*WWD) + wsx;
    #pragma unroll 8
    for (int i = 0; i < 32; ++i) {
      int c = cg*32 + i;
      xv[c*CRD + wsx] = xbase[(size_t)c*(DD*HH*WWD/4)].x;
    }
  }
  __syncthreads();
  // z[r][ws] = sum_c wT[c][r] * xv[c][ws]
  {
    int r = t & 31, wq = t >> 5;
    float a0=0.f,a1=0.f,a2=0.f,a3=0.f;
    #pragma unroll 8
    for (int c = 0; c < CC; ++c) {
      float w = wT[c*33 + r];
      float4 xq = *(const float4*)(xv + c*CRD + wq*4);
      a0 = fmaf(w, xq.x, a0); a1 = fmaf(w, xq.y, a1);
      a2 = fmaf(w, xq.z, a2); a3 = fmaf(w, xq.w, a3);
    }
    zt[r][wq*4+0] = a0; zt[r][wq*4+1] = a1;
    zt[r][wq*4+2] = a2; zt[r][wq*4+3] = a3;
  }
  __syncthreads();
  if (t < 32) {
    float mu = 0.f;
    for (int r = 0; r < 32; ++r) mu += zt[r][t];
    mu *= (1.0f/32.0f);
    float var = 0.f;
    for (int r = 0; r < 32; ++r) { float dl = zt[r][t]-mu; var = fmaf(dl, dl, var); }
    var *= (1.0f/32.0f);
    mu_s[t] = mu; rs_s[t] = 1.0f/sqrtf(var + 1e-5f);
  }
  __syncthreads();
  float* outp = tokn + ((size_t)d*LN + hs*32)*CRD;
  for (int it = t; it < 1024; it += 256) {
    int w2 = it >> 5, r2 = it & 31;
    outp[it] = (zt[r2][w2]-mu_s[w2])*rs_s[w2]*ln_w[r2] + ln_b[r2];
  }
}

// ---------------- K2: prescan (weights-in-registers) + chunk P/h_end ----------------
// rec layout per token (36 floats): [0..1]=dt01, [2..3]=pad, [4..19]=B, [20..35]=C
__global__ __launch_bounds__(256, 3) void bm3d_k2_prescan(
    const float* __restrict__ tokn, const float* __restrict__ ws_inwT,
    const float* __restrict__ ws_xpT,
    const float* __restrict__ cw_f, const float* __restrict__ cb_f,
    const float* __restrict__ dtw_f, const float* __restrict__ dtb_f,
    const float* __restrict__ cw_b, const float* __restrict__ cb_b,
    const float* __restrict__ dtw_b, const float* __restrict__ dtb_b,
    const float* __restrict__ An,
    float* __restrict__ xs_g, float* __restrict__ zs_g, float* __restrict__ rec_g,
    float* __restrict__ P_ws, float* __restrict__ hend_ws) {
  __shared__ float tk[67*CRD];      // 8.6KB
  __shared__ float xr[67*DIN];      // 17.2KB
  __shared__ float xs[64*DIN];      // 16KB
  __shared__ float dbk[64*20];      // 5KB  [r][0..1]=dt01, [4..19]=B
  int b = blockIdx.x;               // 512 = 2 dir * 16 n * 16 g
  int dir = b >> 8, n = (b >> 4) & 15, g = b & 15;
  int l0 = g*CLEN;
  int t = threadIdx.x;
  size_t segbase = ((size_t)dir*NSEQ + n)*LN + l0;   // scan-order token base

  // load tokens (+3 halo) in scan order
  for (int i = t; i < 67*CRD; i += 256) {
    int row = i >> 5, col = i & 31;
    int lb = l0 - 3 + row;
    float v = 0.f;
    if (lb >= 0) {
      int lo = dir ? (LN-1-lb) : lb;
      v = tokn[((size_t)n*LN + lo)*CRD + col];
    }
    tk[i] = v;
  }
  __syncthreads();
  // phase AB: in_proj (x: e<64 -> xr LDS;  z: e>=64 -> silu -> zs_g)
  {
    int ep = t & 63, rq = t >> 6;
    const float* wp = ws_inwT + (size_t)dir*CRD*128 + 2*ep;
    float w0[CRD], w1[CRD];
    #pragma unroll
    for (int dd = 0; dd < CRD; ++dd) {
      float2 wv = *(const float2*)(wp + dd*128);
      w0[dd] = wv.x; w1[dd] = wv.y;
    }
    int r0 = rq*17, r1 = (rq == 3) ? 67 : (r0 + 17);
    for (int r = r0; r < r1; ++r) {
      const float* tkr = tk + r*CRD;
      float a0 = 0.f, a1 = 0.f;
      #pragma unroll
      for (int dq = 0; dq < 8; ++dq) {
        float4 tv = *(const float4*)(tkr + dq*4);
        a0 = fmaf(tv.x, w0[dq*4+0], a0); a1 = fmaf(tv.x, w1[dq*4+0], a1);
        a0 = fmaf(tv.y, w0[dq*4+1], a0); a1 = fmaf(tv.y, w1[dq*4+1], a1);
        a0 = fmaf(tv.z, w0[dq*4+2], a0); a1 = fmaf(tv.z, w1[dq*4+2], a1);
        a0 = fmaf(tv.w, w0[dq*4+3], a0); a1 = fmaf(tv.w, w1[dq*4+3], a1);
      }
      if (ep < 32) {
        xr[r*DIN + 2*ep]   = a0;
        xr[r*DIN + 2*ep+1] = a1;
      } else if (r >= 3) {
        int row = r - 3, e = 2*ep - 64;
        float2 zv = make_float2(siluf(a0), siluf(a1));
        *(float2*)(zs_g + (segbase + row)*DIN + e) = zv;
      }
    }
  }
  __syncthreads();
  // phase C: depthwise conv4 + silu -> xs LDS + xs_g
  {
    const float* cw = dir ? cw_b : cw_f;
    const float* cb = dir ? cb_b : cb_f;
    for (int i = t; i < 64*DIN; i += 256) {
      int r = i >> 6, dd = i & 63;
      float acc = cb[dd];
      #pragma unroll
      for (int k = 0; k < 4; ++k) acc = fmaf(cw[dd*4+k], xr[(r+k)*DIN + dd], acc);
      float v = siluf(acc);
      xs[i] = v;
      xs_g[segbase*DIN + i] = v;
    }
  }
  __syncthreads();
  // phase D1: xproj (e<34): dt01+B -> dbk LDS; all -> rec_g
  {
    int e = t & 63, rq = t >> 6;
    if (e < 34) {
      const float* xwp = ws_xpT + (size_t)dir*DIN*34 + e;
      float xw[DIN];
      #pragma unroll
      for (int dd = 0; dd < DIN; ++dd) xw[dd] = xwp[dd*34];
      int slot = (e < 2) ? e : (e + 2);
      for (int r = rq*16; r < rq*16 + 16; ++r) {
        const float* xsr = xs + r*DIN;
        float acc = 0.f;
        #pragma unroll
        for (int dq = 0; dq < 16; ++dq) {
          float4 xvv = *(const float4*)(xsr + dq*4);
          acc = fmaf(xvv.x, xw[dq*4+0], acc);
          acc = fmaf(xvv.y, xw[dq*4+1], acc);
          acc = fmaf(xvv.z, xw[dq*4+2], acc);
          acc = fmaf(xvv.w, xw[dq*4+3], acc);
        }
        if (e < 18) dbk[r*20 + slot] = acc;
        rec_g[(segbase + r)*36 + slot] = acc;
      }
    }
  }
  __syncthreads();
  // chunk-local scan: P (decay product) and h_end (from h=0)
  {
    int dd = t >> 2, sq = t & 3;
    const float* Ap = An + ((size_t)dir*DIN + dd)*DSTN + sq*4;
    float A0 = Ap[0], A1 = Ap[1], A2 = Ap[2], A3 = Ap[3];
    const float* dtw = dir ? dtw_b : dtw_f;
    const float* dtb = dir ? dtb_b : dtb_f;
    float dw0 = dtw[dd*2+0], dw1 = dtw[dd*2+1], dbb = dtb[dd];
    float h0=0.f,h1=0.f,h2=0.f,h3=0.f, P0=1.f,P1=1.f,P2=1.f,P3=1.f;
    #pragma unroll 4
    for (int i = 0; i < CLEN; ++i) {
      float2 dt01 = *(const float2*)(dbk + i*20);
      float dtv = softplusf(fmaf(dt01.x, dw0, fmaf(dt01.y, dw1, dbb)));
      float xv  = xs[i*DIN + dd];
      float4 Bv = *(const float4*)(dbk + i*20 + 4 + sq*4);
      float dtx = dtv*xv;
      float a0 = __expf(dtv*A0), a1 = __expf(dtv*A1);
      float a2 = __expf(dtv*A2), a3 = __expf(dtv*A3);
      P0 *= a0; P1 *= a1; P2 *= a2; P3 *= a3;
      h0 = fmaf(a0, h0, dtx*Bv.x); h1 = fmaf(a1, h1, dtx*Bv.y);
      h2 = fmaf(a2, h2, dtx*Bv.z); h3 = fmaf(a3, h3, dtx*Bv.w);
    }
    size_t pbase = ((((size_t)dir*NSEQ + n)*GCH + g)*DIN + dd)*DSTN + sq*4;
    *(float4*)(P_ws + pbase)    = make_float4(P0,P1,P2,P3);
    *(float4*)(hend_ws + pbase) = make_float4(h0,h1,h2,h3);
  }
}

// ---------------- K3: both-dir streaming scan + gate + combine + 64->32 proj ----------------
__global__ __launch_bounds__(512) void bm3d_k3_scan(
    const float* __restrict__ xs_g, const float* __restrict__ zs_g,
    const float* __restrict__ rec_g, const float* __restrict__ ws_ow2,
    const float* __restrict__ dtw_f, const float* __restrict__ dtb_f,
    const float* __restrict__ dtw_b, const float* __restrict__ dtb_b,
    const float* __restrict__ An,
    const float* __restrict__ P_ws, const float* __restrict__ hend_ws,
    const float* __restrict__ D_f, const float* __restrict__ D_b,
    float* __restrict__ ym) {
  __shared__ float ys[2*64*65];     // 33.3KB (padded)
  __shared__ float ow[2*DIN*CRD];   // 16KB
  int b = blockIdx.x;               // 256 = 16 n * 16 g
  int n = b >> 4, g = b & 15;
  int t = threadIdx.x;
  for (int i = t; i < 2*DIN*CRD; i += 512) ow[i] = ws_ow2[i];
  // scan: thread = (dir, dd, sq)
  {
    int dir = t >> 8, dd = (t >> 2) & 63, sq = t & 3;
    int gd = dir ? (15 - g) : g;    // scan-order chunk covering this block's tokens
    const float* Ap = An + ((size_t)dir*DIN + dd)*DSTN + sq*4;
    float A0 = Ap[0], A1 = Ap[1], A2 = Ap[2], A3 = Ap[3];
    const float* dtw = dir ? dtw_b : dtw_f;
    const float* dtb = dir ? dtb_b : dtb_f;
    float dw0 = dtw[dd*2+0], dw1 = dtw[dd*2+1], dbb = dtb[dd];
    float Dp = (dir ? D_b : D_f)[dd];
    float h0=0.f,h1=0.f,h2=0.f,h3=0.f;
    for (int gp = 0; gp < gd; ++gp) {
      size_t pb = ((((size_t)dir*NSEQ + n)*GCH + gp)*DIN + dd)*DSTN + sq*4;
      float4 Pv = *(const float4*)(P_ws + pb);
      float4 Hv = *(const float4*)(hend_ws + pb);
      h0 = fmaf(Pv.x, h0, Hv.x); h1 = fmaf(Pv.y, h1, Hv.y);
      h2 = fmaf(Pv.z, h2, Hv.z); h3 = fmaf(Pv.w, h3, Hv.w);
    }
    size_t base = ((size_t)dir*NSEQ + n)*LN + gd*CLEN;
    float* ysd = ys + dir*4160;
    #pragma unroll 2
    for (int i = 0; i < CLEN; ++i) {
      const float* rec = rec_g + (base + i)*36;
      float2 dt01 = *(const float2*)rec;
      float4 Bv = *(const float4*)(rec + 4 + sq*4);
      float4 Cv = *(const float4*)(rec + 20 + sq*4);
      float xv = xs_g[(base + i)*DIN + dd];
      float zv = zs_g[(base + i)*DIN + dd];
      float dtv = softplusf(fmaf(dt01.x, dw0, fmaf(dt01.y, dw1, dbb)));
      float dtx = dtv*xv;
      float a0 = __expf(dtv*A0), a1 = __expf(dtv*A1);
      float a2 = __expf(dtv*A2), a3 = __expf(dtv*A3);
      h0 = fmaf(a0, h0, dtx*Bv.x); h1 = fmaf(a1, h1, dtx*Bv.y);
      h2 = fmaf(a2, h2, dtx*Bv.z); h3 = fmaf(a3, h3, dtx*Bv.w);
      float p = h0*Cv.x + h1*Cv.y + h2*Cv.z + h3*Cv.w;
      p += __shfl_xor(p, 1);
      p += __shfl_xor(p, 2);
      if (sq == 0) {
        int li = dir ? (63 - i) : i;      // original-order index within block
        ysd[li*65 + dd] = (p + Dp*xv)*zv;
      }
    }
  }
  __syncthreads();
  // combine + 64->32 projection: ym[token][r]
  {
    int q = t >> 3, rb = (t & 7) * 4;
    const float* ys0 = ys + q*65;
    const float* ys1 = ys + 4160 + q*65;
    const float* wf = ow;            // ow2[0][dd][r]
    const float* wb = ow + 2048;     // ow2[1][dd][r]
    float a0=0.f,a1=0.f,a2=0.f,a3=0.f;
    #pragma unroll 8
    for (int dd = 0; dd < DIN; ++dd) {
      float yf = ys0[dd], yb = ys1[dd];
      const float* wfr = wf + dd*CRD + rb;
      const float* wbr = wb + dd*CRD + rb;
      a0 = fmaf(yf, wfr[0], fmaf(yb, wbr[0], a0));
      a1 = fmaf(yf, wfr[1], fmaf(yb, wbr[1], a1));
      a2 = fmaf(yf, wfr[2], fmaf(yb, wbr[2], a2));
      a3 = fmaf(yf, wfr[3], fmaf(yb, wbr[3], a3));
    }
    float4 v = make_float4(0.5f*a0, 0.5f*a1, 0.5f*a2, 0.5f*a3);
    *(float4*)(ym + ((size_t)n*LN + g*CLEN + q)*CRD + rb) = v;
  }
}

// ---------------- K45: 32->256 projection + 4x4 upsample (write-bound) ----------------
__global__ __launch_bounds__(256) void bm3d_k45_out(
    const float* __restrict__ ym, const float* __restrict__ w_out,
    float* __restrict__ out) {
  __shared__ float wo[CC*CRD];      // 32KB
  __shared__ float ymt[32*33];      // padded
  int b = blockIdx.x;               // 512 = 16 d * 32 hs
  int d = b >> 5, hs = b & 31;
  int t = threadIdx.x;
  for (int i = t; i < CC*CRD; i += 256) wo[i] = w_out[i];
  const float* fb = ym + ((size_t)d*LN + hs*32)*CRD;
  for (int i = t; i < 1024; i += 256) {
    int wq = i >> 5, r = i & 31;
    ymt[wq*33 + r] = fb[i];
  }
  __syncthreads();
  int q = t & 31, cg = t >> 5;
  const float* fr = ymt + q*33;
  for (int ci = 0; ci < 32; ++ci) {
    int c = cg*32 + ci;
    const float* wr = wo + c*CRD;
    float acc = 0.f;
    #pragma unroll 8
    for (int r = 0; r < 32; ++r) acc = fmaf(wr[r], fr[r], acc);
    f32x4 v = { acc, acc, acc, acc };
    size_t rowbase = (((size_t)c*DD + d)*HH + 4*hs)*WWD + 4*q;
    __builtin_nontemporal_store(v, (f32x4*)(out + rowbase));
    __builtin_nontemporal_store(v, (f32x4*)(out + rowbase +   WWD));
    __builtin_nontemporal_store(v, (f32x4*)(out + rowbase + 2*WWD));
    __builtin_nontemporal_store(v, (f32x4*)(out + rowbase + 3*WWD));
  }
}

extern "C" void kernel_launch(void* const* d_in, const int* in_sizes, int n_in,
                              void* d_out, int out_size, void* d_ws, size_t ws_size,
                              hipStream_t stream) {
  const float* x      = (const float*)d_in[0];
  const float* w_in   = (const float*)d_in[1];
  const float* w_out  = (const float*)d_in[2];
  const float* ln_w   = (const float*)d_in[3];
  const float* ln_b   = (const float*)d_in[4];
  const float* mf_in_w   = (const float*)d_in[5];
  const float* mf_conv_w = (const float*)d_in[6];
  const float* mf_conv_b = (const float*)d_in[7];
  const float* mf_xproj  = (const float*)d_in[8];
  const float* mf_dt_w   = (const float*)d_in[9];
  const float* mf_dt_b   = (const float*)d_in[10];
  const float* mf_A_log  = (const float*)d_in[11];
  const float* mf_D      = (const float*)d_in[12];
  const float* mf_out_w  = (const float*)d_in[13];
  const float* mb_in_w   = (const float*)d_in[14];
  const float* mb_conv_w = (const float*)d_in[15];
  const float* mb_conv_b = (const float*)d_in[16];
  const float* mb_xproj  = (const float*)d_in[17];
  const float* mb_dt_w   = (const float*)d_in[18];
  const float* mb_dt_b   = (const float*)d_in[19];
  const float* mb_A_log  = (const float*)d_in[20];
  const float* mb_D      = (const float*)d_in[21];
  const float* mb_out_w  = (const float*)d_in[22];

  float* ws   = (float*)d_ws;
  float* tokn = ws + OFF_TOKN;
  float* ym   = ws + OFF_YM;
  float* Pw   = ws + OFF_P;
  float* He   = ws + OFF_HE;
  float* xs_g = ws + OFF_XS;
  float* zs_g = ws + OFF_ZS;
  float* recg = ws + OFF_REC;
  float* inwT = ws + OFF_INWT;
  float* xpT  = ws + OFF_XPT;
  float* ow2  = ws + OFF_OW2;
  float* An   = ws + OFF_AN;

  bm3d_k1_token_ln<<<512, 256, 0, stream>>>(x, w_in, ln_w, ln_b,
                                            mf_in_w, mb_in_w, mf_xproj, mb_xproj,
                                            mf_out_w, mb_out_w, mf_A_log, mb_A_log,
                                            tokn, inwT, xpT, ow2, An);
  bm3d_k2_prescan<<<512, 256, 0, stream>>>(tokn, inwT, xpT,
                                           mf_conv_w, mf_conv_b, mf_dt_w, mf_dt_b,
                                           mb_conv_w, mb_conv_b, mb_dt_w, mb_dt_b,
                                           An, xs_g, zs_g, recg, Pw, He);
  bm3d_k3_scan<<<256, 512, 0, stream>>>(xs_g, zs_g, recg, ow2,
                                        mf_dt_w, mf_dt_b, mb_dt_w, mb_dt_b,
                                        An, Pw, He, mf_D, mb_D, ym);
  bm3d_k45_out<<<512, 256, 0, stream>>>(ym, w_out, (float*)d_out);
}